// Round 1
// baseline (154.726 us; speedup 1.0000x reference)
//
#include <hip/hip_runtime.h>
#include <stdint.h>

// OctonionLinear == GEMM: out[b, i*8+k] = sum_{j,p} x[b, j*8+p] * W[i,j,p,k] + bias[i,k]
// M=512 (batch), N=4096 (out_oct*8), K=4096 (in_oct*8), all fp32 in/out.
// Strategy: prep kernel converts x -> bf16 A[512][4096] and weight -> bf16
// B^T[nn][kk] (contiguous K for ds_read_b128 fragments), and writes bias into
// d_out. GEMM: m97-style 128x128 tile, BK=32, global_load_lds(16B), 4 waves
// each computing 64x64 via 4x4 mfma_f32_16x16x32_bf16; K-split x4 (512 blocks
// = 2 blocks/CU) with fp32 atomicAdd epilogue onto the bias-initialized out.
// Workspace use: 4 MB (A bf16) + 32 MB (B^T bf16) = 36 MB.

#define M_DIM 512
#define N_DIM 4096
#define K_DIM 4096
#define KSPLIT 4

typedef __bf16 bf16x8 __attribute__((ext_vector_type(8)));
typedef float f32x4 __attribute__((ext_vector_type(4)));

__device__ inline unsigned short f2bf(float f) {
  union { float f; unsigned int u; } v;
  v.f = f;
  unsigned int u = v.u;
  // round-to-nearest-even bf16
  unsigned int r = (u + 0x7fffu + ((u >> 16) & 1u)) >> 16;
  return (unsigned short)r;
}

// blocks [0,8192): weight transpose+convert -> bt[nn][kk]
// blocks [8192,9216): x convert -> abf (row-major bf16)
// blocks [9216,11264): out = bias (broadcast over batch rows)
__global__ __launch_bounds__(256) void prep_kernel(
    const float* __restrict__ x, const float* __restrict__ w,
    const float* __restrict__ bias, unsigned short* __restrict__ abf,
    unsigned short* __restrict__ bt, float* __restrict__ out) {
  const int bid = blockIdx.x;
  const int tid = threadIdx.x;
  if (bid < 8192) {
    // thread handles (i, j, k): reads block column k over p, writes 8 contiguous bf16
    int g = bid * 256 + tid;            // [0, 512*512*8)
    int k = g & 7;
    int j = (g >> 3) & 511;
    int i = g >> 12;
    const float* wb = w + ((size_t)(i * 512 + j) * 64 + k);
    __attribute__((aligned(16))) unsigned short o[8];
#pragma unroll
    for (int p = 0; p < 8; ++p) o[p] = f2bf(wb[p * 8]);
    *(uint4*)(bt + (size_t)(i * 8 + k) * K_DIM + j * 8) = *(const uint4*)o;
  } else if (bid < 9216) {
    int g = (bid - 8192) * 256 + tid;   // [0, 262144) ; 8 elements each
    const float4* xi = (const float4*)x;
    float4 a = xi[g * 2];
    float4 b = xi[g * 2 + 1];
    __attribute__((aligned(16))) unsigned short o[8] = {
        f2bf(a.x), f2bf(a.y), f2bf(a.z), f2bf(a.w),
        f2bf(b.x), f2bf(b.y), f2bf(b.z), f2bf(b.w)};
    *(uint4*)(abf + (size_t)g * 8) = *(const uint4*)o;
  } else {
    int g = (bid - 9216) * 256 + tid;   // [0, 524288) ; 4 elements each
    int el = g * 4;
    int col = el & (N_DIM - 1);
    *(float4*)(out + el) = *(const float4*)(bias + col);
  }
}

__device__ inline void gld16(const void* g, void* l) {
  __builtin_amdgcn_global_load_lds(
      (const __attribute__((address_space(1))) unsigned int*)g,
      (__attribute__((address_space(3))) unsigned int*)l, 16, 0, 0);
}

__global__ __launch_bounds__(256) void gemm_kernel(
    const unsigned short* __restrict__ A, const unsigned short* __restrict__ Bt,
    float* __restrict__ out) {
  __shared__ __align__(16) unsigned short lA[128 * 32];  // [m][k] 8 KB
  __shared__ __align__(16) unsigned short lB[128 * 32];  // [n][k] 8 KB
  const int t = threadIdx.x;
  const int n0 = blockIdx.x * 128;
  const int m0 = blockIdx.y * 128;
  const int kc0 = blockIdx.z * (K_DIM / KSPLIT);
  const int w = t >> 6;
  const int lane = t & 63;
  const int wr = w >> 1;          // wave row (0..1) -> 64 rows of M
  const int wc = w & 1;           // wave col (0..1) -> 64 cols of N
  const int lrow = lane & 15;
  const int kb = lane >> 4;       // k-block 0..3 (8 bf16 each)

  f32x4 acc[4][4] = {};

  // staging: 512 x 16B per tile; thread issues segments t and t+256.
  // LDS dest = wave-uniform base + lane*16 (contiguous), matching [row][k] packed.
  const int s0 = t, s1 = t + 256;
  const int row0 = s0 >> 2, c0 = (s0 & 3) * 8;
  const int row1 = s1 >> 2, c1 = (s1 & 3) * 8;

  for (int it = 0; it < (K_DIM / KSPLIT) / 32; ++it) {
    const int kk = kc0 + it * 32;
    __syncthreads();  // prior iter's ds_reads done before LDS overwrite
    gld16(A + (size_t)(m0 + row0) * K_DIM + kk + c0, (char*)lA + s0 * 16);
    gld16(Bt + (size_t)(n0 + row0) * K_DIM + kk + c0, (char*)lB + s0 * 16);
    gld16(A + (size_t)(m0 + row1) * K_DIM + kk + c1, (char*)lA + s1 * 16);
    gld16(Bt + (size_t)(n0 + row1) * K_DIM + kk + c1, (char*)lB + s1 * 16);
    __syncthreads();  // compiler drains vmcnt(0) before s_barrier

    bf16x8 af[4], bfr[4];
#pragma unroll
    for (int mt = 0; mt < 4; ++mt)
      af[mt] = *(const bf16x8*)(lA + (wr * 64 + mt * 16 + lrow) * 32 + kb * 8);
#pragma unroll
    for (int nt = 0; nt < 4; ++nt)
      bfr[nt] = *(const bf16x8*)(lB + (wc * 64 + nt * 16 + lrow) * 32 + kb * 8);
#pragma unroll
    for (int mt = 0; mt < 4; ++mt)
#pragma unroll
      for (int nt = 0; nt < 4; ++nt)
        acc[mt][nt] = __builtin_amdgcn_mfma_f32_16x16x32_bf16(
            af[mt], bfr[nt], acc[mt][nt], 0, 0, 0);
  }

  // C/D layout (verified m89/m91): col = lane&15, row = (lane>>4)*4 + reg
#pragma unroll
  for (int mt = 0; mt < 4; ++mt) {
    const int gmb = m0 + wr * 64 + mt * 16 + kb * 4;
#pragma unroll
    for (int nt = 0; nt < 4; ++nt) {
      const int gn = n0 + wc * 64 + nt * 16 + lrow;
#pragma unroll
      for (int r = 0; r < 4; ++r)
        atomicAdd(out + (size_t)(gmb + r) * N_DIM + gn, acc[mt][nt][r]);
    }
  }
}

extern "C" void kernel_launch(void* const* d_in, const int* in_sizes, int n_in,
                              void* d_out, int out_size, void* d_ws,
                              size_t ws_size, hipStream_t stream) {
  const float* x = (const float*)d_in[0];     // [512, 4096]
  const float* w = (const float*)d_in[1];     // [512, 512, 8, 8]
  const float* bias = (const float*)d_in[2];  // [512, 8]
  float* out = (float*)d_out;                 // [512, 4096]

  unsigned short* abf = (unsigned short*)d_ws;              // 4 MB bf16 A
  unsigned short* bt = abf + (size_t)M_DIM * K_DIM;         // 32 MB bf16 B^T

  prep_kernel<<<11264, 256, 0, stream>>>(x, w, bias, abf, bt, out);

  dim3 grid(N_DIM / 128, M_DIM / 128, KSPLIT);  // 32 x 4 x 4 = 512 blocks
  gemm_kernel<<<grid, 256, 0, stream>>>(abf, bt, out);
}